// Round 5
// baseline (719.456 us; speedup 1.0000x reference)
//
#include <hip/hip_runtime.h>
#include <hip/hip_bf16.h>

#define NEG_SLOPE 0.2f
#define BSHIFT 6                       // 64 nodes per bucket
#define BNODES (1 << BSHIFT)

// ---------------- CSR build: deg + scan ----------------

__global__ __launch_bounds__(256) void init_deg_kernel(int* __restrict__ deg, int N)
{
    int i = blockIdx.x * blockDim.x + threadIdx.x;
    if (i < N) deg[i] = 1;  // self-loop
}

__global__ __launch_bounds__(256) void count_deg_kernel(
    const int* __restrict__ adj, int* __restrict__ deg, int E)
{
    int e = blockIdx.x * blockDim.x + threadIdx.x;
    if (e < E) atomicAdd(&deg[adj[E + e]], 1);
}

__global__ __launch_bounds__(1024) void scan1_kernel(
    const int* __restrict__ deg, int* __restrict__ row_ptr, int* __restrict__ bsum, int N)
{
    __shared__ int s[1024];
    int i = blockIdx.x * 1024 + threadIdx.x;
    int v = (i < N) ? deg[i] : 0;
    s[threadIdx.x] = v;
    __syncthreads();
    for (int off = 1; off < 1024; off <<= 1) {
        int t = (threadIdx.x >= off) ? s[threadIdx.x - off] : 0;
        __syncthreads();
        s[threadIdx.x] += t;
        __syncthreads();
    }
    if (i < N) row_ptr[i + 1] = s[threadIdx.x];
    if (threadIdx.x == 1023) bsum[blockIdx.x] = s[1023];
}

__global__ __launch_bounds__(1024) void scan2_kernel(int* __restrict__ bsum, int NB)
{
    __shared__ int s[1024];
    int t = threadIdx.x;
    int v = (t < NB) ? bsum[t] : 0;
    s[t] = v;
    __syncthreads();
    for (int off = 1; off < 1024; off <<= 1) {
        int u = (t >= off) ? s[t - off] : 0;
        __syncthreads();
        s[t] += u;
        __syncthreads();
    }
    if (t < NB) bsum[t] = s[t] - v;
}

__global__ __launch_bounds__(256) void scan3_kernel(
    int* __restrict__ row_ptr, const int* __restrict__ bsum, int N)
{
    int i = blockIdx.x * blockDim.x + threadIdx.x;
    if (i >= N) return;
    row_ptr[i + 1] += bsum[i >> 10];
    if (i == 0) row_ptr[0] = 0;
}

// gcur[b] = row_ptr[b*64]  (bucket base in edge space; self-loops included)
__global__ __launch_bounds__(256) void bucket_base_kernel(
    const int* __restrict__ row_ptr, int* __restrict__ gcur, int NBK)
{
    int b = blockIdx.x * blockDim.x + threadIdx.x;
    if (b < NBK) gcur[b] = row_ptr[b << BSHIFT];
}

// Phase A: partition edges into buckets of 64 dst nodes. pbuf entry = (src<<6)|local.
__global__ __launch_bounds__(256) void partition_kernel(
    const int* __restrict__ adj, int* __restrict__ gcur,
    int* __restrict__ pbuf, int E, int N)
{
    int e = blockIdx.x * blockDim.x + threadIdx.x;
    if (e >= E + N) return;
    int s, d;
    if (e < E) { s = adj[e]; d = adj[E + e]; } else { s = d = e - E; }
    int bucket = d >> BSHIFT;
    int pos = atomicAdd(&gcur[bucket], 1);
    pbuf[pos] = (s << BSHIFT) | (d & (BNODES - 1));
}

// Phase B: one workgroup per bucket; LDS cursors; writes land in a ~4KB window.
__global__ __launch_bounds__(256) void csr_build_kernel(
    const int* __restrict__ row_ptr, const int* __restrict__ pbuf,
    int* __restrict__ col_idx, int N)
{
    __shared__ int lcur[BNODES];
    int b = blockIdx.x;
    int node0 = b << BSHIFT;
    int nn = min(BNODES, N - node0);
    int t = threadIdx.x;
    if (t < nn) lcur[t] = row_ptr[node0 + t];
    __syncthreads();
    int beg = row_ptr[node0];
    int end = row_ptr[node0 + nn];
    for (int i = beg + t; i < end; i += 256) {
        int p = pbuf[i];
        int local = p & (BNODES - 1);
        int src = p >> BSHIFT;
        int pos = atomicAdd(&lcur[local], 1);
        col_idx[pos] = src;
    }
}

// ---------------- dense pieces ----------------

// h = X @ W ; as[n]=h·a_src ; ad[n]=h·a_dst. 32 rows/block, 8 rows/wave,
// k-outer so each Ws element is reused across 8 rows.
template<int K>
__global__ __launch_bounds__(256) void gemm_alpha_kernel(
    const float* __restrict__ X, const float* __restrict__ W,
    const float* __restrict__ a_src, const float* __restrict__ a_dst,
    float* __restrict__ h, float* __restrict__ as_, float* __restrict__ ad_, int N)
{
    __shared__ float Ws[K * 64];
    __shared__ float Xs[32 * K];
    const int t = threadIdx.x;
    for (int i = t * 4; i < K * 64; i += 1024)
        *(float4*)(Ws + i) = *(const float4*)(W + i);
    const int row0 = blockIdx.x * 32;
    for (int i = t * 4; i < 32 * K; i += 1024) {
        int r = row0 + i / K;
        float4 v = make_float4(0.f, 0.f, 0.f, 0.f);
        if (r < N) v = *(const float4*)(X + (size_t)r * K + (i % K));
        *(float4*)(Xs + i) = v;
    }
    __syncthreads();
    const int wave = t >> 6, lane = t & 63;
    const float* xb = &Xs[wave * 8 * K];
    float acc[8] = {0.f, 0.f, 0.f, 0.f, 0.f, 0.f, 0.f, 0.f};
#pragma unroll 4
    for (int k4 = 0; k4 < K; k4 += 4) {
        float w0 = Ws[(k4 + 0) * 64 + lane];
        float w1 = Ws[(k4 + 1) * 64 + lane];
        float w2 = Ws[(k4 + 2) * 64 + lane];
        float w3 = Ws[(k4 + 3) * 64 + lane];
#pragma unroll
        for (int rr = 0; rr < 8; ++rr) {
            float4 xv = *(const float4*)(xb + rr * K + k4);
            acc[rr] += xv.x * w0 + xv.y * w1 + xv.z * w2 + xv.w * w3;
        }
    }
    const float a_s = a_src[lane], a_d = a_dst[lane];
#pragma unroll
    for (int rr = 0; rr < 8; ++rr) {
        int row = row0 + wave * 8 + rr;
        if (row >= N) break;
        float a = acc[rr];
        h[(size_t)row * 64 + lane] = a;
        float va = a * a_s, vd = a * a_d;
#pragma unroll
        for (int off = 32; off > 0; off >>= 1) {
            va += __shfl_down(va, off, 64);
            vd += __shfl_down(vd, off, 64);
        }
        if (lane == 0) { as_[row] = va; ad_[row] = vd; }
    }
}

// Fused softmax+aggregate: one wave per dst node, 16 edges per loop step
// (4 sub-groups of 16 lanes × 4-deep unroll), float4 over the 64-dim row.
__global__ __launch_bounds__(256) void gat_aggregate_kernel(
    const int* __restrict__ row_ptr, const int* __restrict__ col_idx,
    const float* __restrict__ as_, const float* __restrict__ ad_,
    const float* __restrict__ h, const float* __restrict__ b,
    float* __restrict__ out, int N, int do_elu)
{
    int node = blockIdx.x * 4 + (threadIdx.x >> 6);
    int lane = threadIdx.x & 63;
    int sub = lane >> 4, q = lane & 15;
    if (node >= N) return;
    int beg = row_ptr[node], end = row_ptr[node + 1];
    float ad = ad_[node];
    float4 acc = make_float4(0.f, 0.f, 0.f, 0.f);
    float psum = 0.f;
    for (int i = beg; i < end; i += 16) {
        int e0 = i + sub, e1 = i + 4 + sub, e2 = i + 8 + sub, e3 = i + 12 + sub;
        bool v0 = e0 < end, v1 = e1 < end, v2 = e2 < end, v3 = e3 < end;
        int s0 = col_idx[v0 ? e0 : end - 1];
        int s1 = col_idx[v1 ? e1 : end - 1];
        int s2 = col_idx[v2 ? e2 : end - 1];
        int s3 = col_idx[v3 ? e3 : end - 1];
        float x0 = as_[s0] + ad, x1 = as_[s1] + ad;
        float x2 = as_[s2] + ad, x3 = as_[s3] + ad;
        float4 f0 = ((const float4*)(h + (size_t)s0 * 64))[q];
        float4 f1 = ((const float4*)(h + (size_t)s1 * 64))[q];
        float4 f2 = ((const float4*)(h + (size_t)s2 * 64))[q];
        float4 f3 = ((const float4*)(h + (size_t)s3 * 64))[q];
        x0 = x0 > 0.f ? x0 : NEG_SLOPE * x0;
        x1 = x1 > 0.f ? x1 : NEG_SLOPE * x1;
        x2 = x2 > 0.f ? x2 : NEG_SLOPE * x2;
        x3 = x3 > 0.f ? x3 : NEG_SLOPE * x3;
        float p0 = v0 ? __expf(x0) : 0.f;
        float p1 = v1 ? __expf(x1) : 0.f;
        float p2 = v2 ? __expf(x2) : 0.f;
        float p3 = v3 ? __expf(x3) : 0.f;
        psum += (p0 + p1) + (p2 + p3);
        acc.x += p0 * f0.x + p1 * f1.x + p2 * f2.x + p3 * f3.x;
        acc.y += p0 * f0.y + p1 * f1.y + p2 * f2.y + p3 * f3.y;
        acc.z += p0 * f0.z + p1 * f1.z + p2 * f2.z + p3 * f3.z;
        acc.w += p0 * f0.w + p1 * f1.w + p2 * f2.w + p3 * f3.w;
    }
#pragma unroll
    for (int off = 16; off <= 32; off <<= 1) {
        acc.x += __shfl_xor(acc.x, off, 64);
        acc.y += __shfl_xor(acc.y, off, 64);
        acc.z += __shfl_xor(acc.z, off, 64);
        acc.w += __shfl_xor(acc.w, off, 64);
        psum  += __shfl_xor(psum,  off, 64);
    }
    if (sub == 0) {
        float inv = 1.f / psum;
        float4 bb = ((const float4*)b)[q];
        float4 v;
        v.x = acc.x * inv + bb.x;
        v.y = acc.y * inv + bb.y;
        v.z = acc.z * inv + bb.z;
        v.w = acc.w * inv + bb.w;
        if (do_elu) {
            v.x = v.x > 0.f ? v.x : (__expf(v.x) - 1.f);
            v.y = v.y > 0.f ? v.y : (__expf(v.y) - 1.f);
            v.z = v.z > 0.f ? v.z : (__expf(v.z) - 1.f);
            v.w = v.w > 0.f ? v.w : (__expf(v.w) - 1.f);
        }
        ((float4*)(out + (size_t)node * 64))[q] = v;
    }
}

// logits[n][c] = x[n]·cW[:,c] + cb[c]
__global__ __launch_bounds__(256) void classifier_kernel(
    const float* __restrict__ x, const float* __restrict__ cw,
    const float* __restrict__ cb, float* __restrict__ out, int N)
{
    int i = blockIdx.x * blockDim.x + threadIdx.x;
    if (i >= N * 16) return;
    int n = i >> 4, c = i & 15;
    const float4* xr = (const float4*)(x + (size_t)n * 64);
    float acc = cb[c];
#pragma unroll
    for (int j4 = 0; j4 < 16; ++j4) {
        float4 xv = xr[j4];
        acc += xv.x * cw[(j4 * 4 + 0) * 16 + c];
        acc += xv.y * cw[(j4 * 4 + 1) * 16 + c];
        acc += xv.z * cw[(j4 * 4 + 2) * 16 + c];
        acc += xv.w * cw[(j4 * 4 + 3) * 16 + c];
    }
    out[i] = acc;
}

extern "C" void kernel_launch(void* const* d_in, const int* in_sizes, int n_in,
                              void* d_out, int out_size, void* d_ws, size_t ws_size,
                              hipStream_t stream)
{
    const float* X    = (const float*)d_in[0];
    const int*   adj  = (const int*)d_in[1];
    const float* W1   = (const float*)d_in[2];
    const float* a_s1 = (const float*)d_in[3];
    const float* a_d1 = (const float*)d_in[4];
    const float* b1   = (const float*)d_in[5];
    const float* W2   = (const float*)d_in[6];
    const float* a_s2 = (const float*)d_in[7];
    const float* a_d2 = (const float*)d_in[8];
    const float* b2   = (const float*)d_in[9];
    const float* cW   = (const float*)d_in[10];
    const float* cb   = (const float*)d_in[11];

    const int N   = in_sizes[0] / 128;
    const int E   = in_sizes[1] / 2;
    const int ET  = E + N;
    const int NB  = (N + 1023) / 1024;
    const int NBK = (N + BNODES - 1) >> BSHIFT;   // buckets

    float* A       = (float*)d_ws;            // h,        N*64
    float* B       = A + (size_t)N * 64;      // layer1 x, N*64
    float* asb     = B + (size_t)N * 64;      // N
    float* adb     = asb + N;                 // N
    int*   deg     = (int*)(adb + N);         // N
    int*   row_ptr = deg + N;                 // N+1
    int*   col_idx = row_ptr + (N + 1);       // E+N
    int*   pbuf    = col_idx + ET;            // E+N
    int*   gcur    = pbuf + ET;               // NBK
    int*   bsum    = gcur + NBK;              // NB

    const int T = 256;
    const int nodeBlocks  = (N + T - 1) / T;
    const int edgeBlocksE = (E + T - 1) / T;
    const int edgeBlocksT = (ET + T - 1) / T;
    const int gemmBlocks  = (N + 31) / 32;
    const int aggBlocks   = (N + 3) / 4;

    // ---- CSR build (once, reused by both layers) ----
    init_deg_kernel<<<nodeBlocks, T, 0, stream>>>(deg, N);
    count_deg_kernel<<<edgeBlocksE, T, 0, stream>>>(adj, deg, E);
    scan1_kernel<<<NB, 1024, 0, stream>>>(deg, row_ptr, bsum, N);
    scan2_kernel<<<1, 1024, 0, stream>>>(bsum, NB);
    scan3_kernel<<<nodeBlocks, T, 0, stream>>>(row_ptr, bsum, N);
    bucket_base_kernel<<<(NBK + T - 1) / T, T, 0, stream>>>(row_ptr, gcur, NBK);
    partition_kernel<<<edgeBlocksT, T, 0, stream>>>(adj, gcur, pbuf, E, N);
    csr_build_kernel<<<NBK, T, 0, stream>>>(row_ptr, pbuf, col_idx, N);

    // ---- layer 1 ----
    gemm_alpha_kernel<128><<<gemmBlocks, T, 0, stream>>>(
        X, W1, a_s1, a_d1, A, asb, adb, N);
    gat_aggregate_kernel<<<aggBlocks, T, 0, stream>>>(
        row_ptr, col_idx, asb, adb, A, b1, B, N, 1);

    // ---- layer 2 (x written straight into d_out tail) ----
    float* out  = (float*)d_out;
    float* xout = out + (size_t)N * 16;
    gemm_alpha_kernel<64><<<gemmBlocks, T, 0, stream>>>(
        B, W2, a_s2, a_d2, A, asb, adb, N);
    gat_aggregate_kernel<<<aggBlocks, T, 0, stream>>>(
        row_ptr, col_idx, asb, adb, A, b2, xout, N, 0);

    // ---- classifier ----
    classifier_kernel<<<(N * 16 + T - 1) / T, T, 0, stream>>>(
        xout, cW, cb, out, N);
}

// Round 6
// 538.054 us; speedup vs baseline: 1.3371x; 1.3371x over previous
//
#include <hip/hip_runtime.h>
#include <hip/hip_bf16.h>

#define NEG_SLOPE 0.2f

// ---------------- CSR build (counting sort by dst) ----------------

__global__ __launch_bounds__(256) void init_deg_kernel(int* __restrict__ deg, int N)
{
    int i = blockIdx.x * blockDim.x + threadIdx.x;
    if (i < N) deg[i] = 1;  // self-loop
}

__global__ __launch_bounds__(256) void count_deg_kernel(
    const int* __restrict__ adj, int* __restrict__ deg, int E)
{
    int e = blockIdx.x * blockDim.x + threadIdx.x;
    if (e < E) atomicAdd(&deg[adj[E + e]], 1);
}

__global__ __launch_bounds__(1024) void scan1_kernel(
    const int* __restrict__ deg, int* __restrict__ row_ptr, int* __restrict__ bsum, int N)
{
    __shared__ int s[1024];
    int i = blockIdx.x * 1024 + threadIdx.x;
    int v = (i < N) ? deg[i] : 0;
    s[threadIdx.x] = v;
    __syncthreads();
    for (int off = 1; off < 1024; off <<= 1) {
        int t = (threadIdx.x >= off) ? s[threadIdx.x - off] : 0;
        __syncthreads();
        s[threadIdx.x] += t;
        __syncthreads();
    }
    if (i < N) row_ptr[i + 1] = s[threadIdx.x];
    if (threadIdx.x == 1023) bsum[blockIdx.x] = s[1023];
}

__global__ __launch_bounds__(1024) void scan2_kernel(int* __restrict__ bsum, int NB)
{
    __shared__ int s[1024];
    int t = threadIdx.x;
    int v = (t < NB) ? bsum[t] : 0;
    s[t] = v;
    __syncthreads();
    for (int off = 1; off < 1024; off <<= 1) {
        int u = (t >= off) ? s[t - off] : 0;
        __syncthreads();
        s[t] += u;
        __syncthreads();
    }
    if (t < NB) bsum[t] = s[t] - v;
}

// apply block offsets; cursor[i] = exclusive scan = row start
__global__ __launch_bounds__(256) void scan3_kernel(
    int* __restrict__ row_ptr, int* __restrict__ cursor,
    const int* __restrict__ deg, const int* __restrict__ bsum, int N)
{
    int i = blockIdx.x * blockDim.x + threadIdx.x;
    if (i >= N) return;
    int r = row_ptr[i + 1] + bsum[i >> 10];
    row_ptr[i + 1] = r;
    cursor[i] = r - deg[i];
    if (i == 0) row_ptr[0] = 0;
}

// per-node cursors: ~17 atomics per counter, no same-address contention hot-spot
__global__ __launch_bounds__(256) void scatter_kernel(
    const int* __restrict__ adj, int* __restrict__ cursor,
    int* __restrict__ col_idx, int E, int N)
{
    int e = blockIdx.x * blockDim.x + threadIdx.x;
    if (e >= E + N) return;
    int s, d;
    if (e < E) { s = adj[e]; d = adj[E + e]; } else { s = d = e - E; }
    int pos = atomicAdd(&cursor[d], 1);
    col_idx[pos] = s;
}

// ---------------- dense pieces ----------------

__device__ __forceinline__ float bf_to_f(unsigned short u)
{
    return __uint_as_float((unsigned)u << 16);
}

// h = X @ W (h stored bf16); as[n]=h·a_src ; ad[n]=h·a_dst (f32 precision).
// 32 rows/block, 8 rows/wave, k-outer so each Ws element is reused across 8 rows.
template<int K>
__global__ __launch_bounds__(256) void gemm_alpha_kernel(
    const float* __restrict__ X, const float* __restrict__ W,
    const float* __restrict__ a_src, const float* __restrict__ a_dst,
    __hip_bfloat16* __restrict__ h, float* __restrict__ as_, float* __restrict__ ad_, int N)
{
    __shared__ float Ws[K * 64];
    __shared__ float Xs[32 * K];
    const int t = threadIdx.x;
    for (int i = t * 4; i < K * 64; i += 1024)
        *(float4*)(Ws + i) = *(const float4*)(W + i);
    const int row0 = blockIdx.x * 32;
    for (int i = t * 4; i < 32 * K; i += 1024) {
        int r = row0 + i / K;
        float4 v = make_float4(0.f, 0.f, 0.f, 0.f);
        if (r < N) v = *(const float4*)(X + (size_t)r * K + (i % K));
        *(float4*)(Xs + i) = v;
    }
    __syncthreads();
    const int wave = t >> 6, lane = t & 63;
    const float* xb = &Xs[wave * 8 * K];
    float acc[8] = {0.f, 0.f, 0.f, 0.f, 0.f, 0.f, 0.f, 0.f};
#pragma unroll 4
    for (int k4 = 0; k4 < K; k4 += 4) {
        float w0 = Ws[(k4 + 0) * 64 + lane];
        float w1 = Ws[(k4 + 1) * 64 + lane];
        float w2 = Ws[(k4 + 2) * 64 + lane];
        float w3 = Ws[(k4 + 3) * 64 + lane];
#pragma unroll
        for (int rr = 0; rr < 8; ++rr) {
            float4 xv = *(const float4*)(xb + rr * K + k4);
            acc[rr] += xv.x * w0 + xv.y * w1 + xv.z * w2 + xv.w * w3;
        }
    }
    const float a_s = a_src[lane], a_d = a_dst[lane];
#pragma unroll
    for (int rr = 0; rr < 8; ++rr) {
        int row = row0 + wave * 8 + rr;
        if (row >= N) break;
        float a = acc[rr];
        h[(size_t)row * 64 + lane] = __float2bfloat16(a);
        float va = a * a_s, vd = a * a_d;
#pragma unroll
        for (int off = 32; off > 0; off >>= 1) {
            va += __shfl_down(va, off, 64);
            vd += __shfl_down(vd, off, 64);
        }
        if (lane == 0) { as_[row] = va; ad_[row] = vd; }
    }
}

// Fused softmax+aggregate: one wave per dst node, 16 edges per loop step
// (4 sub-groups of 16 lanes x 4-deep unroll), bf16x4 (8B) loads over the 64-dim row.
__global__ __launch_bounds__(256) void gat_aggregate_kernel(
    const int* __restrict__ row_ptr, const int* __restrict__ col_idx,
    const float* __restrict__ as_, const float* __restrict__ ad_,
    const __hip_bfloat16* __restrict__ h, const float* __restrict__ b,
    float* __restrict__ out, int N, int do_elu)
{
    int node = blockIdx.x * 4 + (threadIdx.x >> 6);
    int lane = threadIdx.x & 63;
    int sub = lane >> 4, q = lane & 15;
    if (node >= N) return;
    int beg = row_ptr[node], end = row_ptr[node + 1];
    float ad = ad_[node];
    float4 acc = make_float4(0.f, 0.f, 0.f, 0.f);
    float psum = 0.f;
    const ushort4* hb = (const ushort4*)h;
    for (int i = beg; i < end; i += 16) {
        int e0 = i + sub, e1 = i + 4 + sub, e2 = i + 8 + sub, e3 = i + 12 + sub;
        bool v0 = e0 < end, v1 = e1 < end, v2 = e2 < end, v3 = e3 < end;
        int s0 = col_idx[v0 ? e0 : end - 1];
        int s1 = col_idx[v1 ? e1 : end - 1];
        int s2 = col_idx[v2 ? e2 : end - 1];
        int s3 = col_idx[v3 ? e3 : end - 1];
        float x0 = as_[s0] + ad, x1 = as_[s1] + ad;
        float x2 = as_[s2] + ad, x3 = as_[s3] + ad;
        ushort4 u0 = hb[(size_t)s0 * 16 + q];
        ushort4 u1 = hb[(size_t)s1 * 16 + q];
        ushort4 u2 = hb[(size_t)s2 * 16 + q];
        ushort4 u3 = hb[(size_t)s3 * 16 + q];
        x0 = x0 > 0.f ? x0 : NEG_SLOPE * x0;
        x1 = x1 > 0.f ? x1 : NEG_SLOPE * x1;
        x2 = x2 > 0.f ? x2 : NEG_SLOPE * x2;
        x3 = x3 > 0.f ? x3 : NEG_SLOPE * x3;
        float p0 = v0 ? __expf(x0) : 0.f;
        float p1 = v1 ? __expf(x1) : 0.f;
        float p2 = v2 ? __expf(x2) : 0.f;
        float p3 = v3 ? __expf(x3) : 0.f;
        psum += (p0 + p1) + (p2 + p3);
        acc.x += p0 * bf_to_f(u0.x) + p1 * bf_to_f(u1.x) + p2 * bf_to_f(u2.x) + p3 * bf_to_f(u3.x);
        acc.y += p0 * bf_to_f(u0.y) + p1 * bf_to_f(u1.y) + p2 * bf_to_f(u2.y) + p3 * bf_to_f(u3.y);
        acc.z += p0 * bf_to_f(u0.z) + p1 * bf_to_f(u1.z) + p2 * bf_to_f(u2.z) + p3 * bf_to_f(u3.z);
        acc.w += p0 * bf_to_f(u0.w) + p1 * bf_to_f(u1.w) + p2 * bf_to_f(u2.w) + p3 * bf_to_f(u3.w);
    }
#pragma unroll
    for (int off = 16; off <= 32; off <<= 1) {
        acc.x += __shfl_xor(acc.x, off, 64);
        acc.y += __shfl_xor(acc.y, off, 64);
        acc.z += __shfl_xor(acc.z, off, 64);
        acc.w += __shfl_xor(acc.w, off, 64);
        psum  += __shfl_xor(psum,  off, 64);
    }
    if (sub == 0) {
        float inv = 1.f / psum;
        float4 bb = ((const float4*)b)[q];
        float4 v;
        v.x = acc.x * inv + bb.x;
        v.y = acc.y * inv + bb.y;
        v.z = acc.z * inv + bb.z;
        v.w = acc.w * inv + bb.w;
        if (do_elu) {
            v.x = v.x > 0.f ? v.x : (__expf(v.x) - 1.f);
            v.y = v.y > 0.f ? v.y : (__expf(v.y) - 1.f);
            v.z = v.z > 0.f ? v.z : (__expf(v.z) - 1.f);
            v.w = v.w > 0.f ? v.w : (__expf(v.w) - 1.f);
        }
        ((float4*)(out + (size_t)node * 64))[q] = v;
    }
}

// logits[n][c] = x[n]·cW[:,c] + cb[c]
__global__ __launch_bounds__(256) void classifier_kernel(
    const float* __restrict__ x, const float* __restrict__ cw,
    const float* __restrict__ cb, float* __restrict__ out, int N)
{
    int i = blockIdx.x * blockDim.x + threadIdx.x;
    if (i >= N * 16) return;
    int n = i >> 4, c = i & 15;
    const float4* xr = (const float4*)(x + (size_t)n * 64);
    float acc = cb[c];
#pragma unroll
    for (int j4 = 0; j4 < 16; ++j4) {
        float4 xv = xr[j4];
        acc += xv.x * cw[(j4 * 4 + 0) * 16 + c];
        acc += xv.y * cw[(j4 * 4 + 1) * 16 + c];
        acc += xv.z * cw[(j4 * 4 + 2) * 16 + c];
        acc += xv.w * cw[(j4 * 4 + 3) * 16 + c];
    }
    out[i] = acc;
}

extern "C" void kernel_launch(void* const* d_in, const int* in_sizes, int n_in,
                              void* d_out, int out_size, void* d_ws, size_t ws_size,
                              hipStream_t stream)
{
    const float* X    = (const float*)d_in[0];
    const int*   adj  = (const int*)d_in[1];
    const float* W1   = (const float*)d_in[2];
    const float* a_s1 = (const float*)d_in[3];
    const float* a_d1 = (const float*)d_in[4];
    const float* b1   = (const float*)d_in[5];
    const float* W2   = (const float*)d_in[6];
    const float* a_s2 = (const float*)d_in[7];
    const float* a_d2 = (const float*)d_in[8];
    const float* b2   = (const float*)d_in[9];
    const float* cW   = (const float*)d_in[10];
    const float* cb   = (const float*)d_in[11];

    const int N  = in_sizes[0] / 128;
    const int E  = in_sizes[1] / 2;
    const int ET = E + N;
    const int NB = (N + 1023) / 1024;

    __hip_bfloat16* A = (__hip_bfloat16*)d_ws;        // h (bf16), N*64
    float* B       = (float*)(A + (size_t)N * 64);    // layer1 x, N*64 f32
    float* asb     = B + (size_t)N * 64;              // N
    float* adb     = asb + N;                         // N
    int*   deg     = (int*)(adb + N);                 // N
    int*   cursor  = deg + N;                         // N
    int*   row_ptr = cursor + N;                      // N+1
    int*   col_idx = row_ptr + (N + 1);               // E+N
    int*   bsum    = col_idx + ET;                    // NB (<=1024)

    const int T = 256;
    const int nodeBlocks  = (N + T - 1) / T;
    const int edgeBlocksE = (E + T - 1) / T;
    const int edgeBlocksT = (ET + T - 1) / T;
    const int gemmBlocks  = (N + 31) / 32;
    const int aggBlocks   = (N + 3) / 4;

    // ---- CSR build (once, reused by both layers) ----
    init_deg_kernel<<<nodeBlocks, T, 0, stream>>>(deg, N);
    count_deg_kernel<<<edgeBlocksE, T, 0, stream>>>(adj, deg, E);
    scan1_kernel<<<NB, 1024, 0, stream>>>(deg, row_ptr, bsum, N);
    scan2_kernel<<<1, 1024, 0, stream>>>(bsum, NB);
    scan3_kernel<<<nodeBlocks, T, 0, stream>>>(row_ptr, cursor, deg, bsum, N);
    scatter_kernel<<<edgeBlocksT, T, 0, stream>>>(adj, cursor, col_idx, E, N);

    // ---- layer 1 ----
    gemm_alpha_kernel<128><<<gemmBlocks, T, 0, stream>>>(
        X, W1, a_s1, a_d1, A, asb, adb, N);
    gat_aggregate_kernel<<<aggBlocks, T, 0, stream>>>(
        row_ptr, col_idx, asb, adb, A, b1, B, N, 1);

    // ---- layer 2 (x written straight into d_out tail) ----
    float* out  = (float*)d_out;
    float* xout = out + (size_t)N * 16;
    gemm_alpha_kernel<64><<<gemmBlocks, T, 0, stream>>>(
        B, W2, a_s2, a_d2, A, asb, adb, N);
    gat_aggregate_kernel<<<aggBlocks, T, 0, stream>>>(
        row_ptr, col_idx, asb, adb, A, b2, xout, N, 0);

    // ---- classifier ----
    classifier_kernel<<<(N * 16 + T - 1) / T, T, 0, stream>>>(
        xout, cW, cb, out, N);
}

// Round 7
// 500.801 us; speedup vs baseline: 1.4366x; 1.0744x over previous
//
#include <hip/hip_runtime.h>
#include <hip/hip_bf16.h>

#define NEG_SLOPE 0.2f
#define NSLICE 8                 // one dst-range slice per XCD
#define SLICE_WGS 128            // workgroups per slice
#define SCAT_GRID (NSLICE * SLICE_WGS)

// ---------------- CSR build (counting sort by dst) ----------------

__global__ __launch_bounds__(256) void init_deg_kernel(int* __restrict__ deg, int N)
{
    int i = blockIdx.x * blockDim.x + threadIdx.x;
    if (i < N) deg[i] = 1;  // self-loop
}

// dst-sliced degree count: slice s only touches deg[lo,hi) -> XCD-local atomic lines
__global__ __launch_bounds__(256) void count_deg_sliced_kernel(
    const int* __restrict__ adj, int* __restrict__ deg, int E, int N, int W)
{
    int slice = blockIdx.x % NSLICE;
    int gs    = blockIdx.x / NSLICE;
    int lo = slice * W, hi = min(N, lo + W);
    int stride = SLICE_WGS * 256;
    for (int e = gs * 256 + threadIdx.x; e < E; e += stride) {
        int d = __builtin_nontemporal_load(adj + E + e);
        if (d < lo || d >= hi) continue;
        atomicAdd(&deg[d], 1);
    }
}

__global__ __launch_bounds__(1024) void scan1_kernel(
    const int* __restrict__ deg, int* __restrict__ row_ptr, int* __restrict__ bsum, int N)
{
    __shared__ int s[1024];
    int i = blockIdx.x * 1024 + threadIdx.x;
    int v = (i < N) ? deg[i] : 0;
    s[threadIdx.x] = v;
    __syncthreads();
    for (int off = 1; off < 1024; off <<= 1) {
        int t = (threadIdx.x >= off) ? s[threadIdx.x - off] : 0;
        __syncthreads();
        s[threadIdx.x] += t;
        __syncthreads();
    }
    if (i < N) row_ptr[i + 1] = s[threadIdx.x];
    if (threadIdx.x == 1023) bsum[blockIdx.x] = s[1023];
}

__global__ __launch_bounds__(1024) void scan2_kernel(int* __restrict__ bsum, int NB)
{
    __shared__ int s[1024];
    int t = threadIdx.x;
    int v = (t < NB) ? bsum[t] : 0;
    s[t] = v;
    __syncthreads();
    for (int off = 1; off < 1024; off <<= 1) {
        int u = (t >= off) ? s[t - off] : 0;
        __syncthreads();
        s[t] += u;
        __syncthreads();
    }
    if (t < NB) bsum[t] = s[t] - v;
}

// apply block offsets; cursor[i] = exclusive scan = row start
__global__ __launch_bounds__(256) void scan3_kernel(
    int* __restrict__ row_ptr, int* __restrict__ cursor,
    const int* __restrict__ deg, const int* __restrict__ bsum, int N)
{
    int i = blockIdx.x * blockDim.x + threadIdx.x;
    if (i >= N) return;
    int r = row_ptr[i + 1] + bsum[i >> 10];
    row_ptr[i + 1] = r;
    cursor[i] = r - deg[i];
    if (i == 0) row_ptr[0] = 0;
}

// dst-sliced scatter: slice s writes only col_idx[row_ptr[lo]..row_ptr[hi]) (~850KB)
// and cursors[lo..hi) (~50KB) -> stays resident in one XCD L2, lines fill fully.
__global__ __launch_bounds__(256) void scatter_sliced_kernel(
    const int* __restrict__ adj, int* __restrict__ cursor,
    int* __restrict__ col_idx, int E, int N, int W)
{
    int slice = blockIdx.x % NSLICE;
    int gs    = blockIdx.x / NSLICE;
    int lo = slice * W, hi = min(N, lo + W);
    int ET = E + N;
    int stride = SLICE_WGS * 256;
    for (int e = gs * 256 + threadIdx.x; e < ET; e += stride) {
        int s, d;
        if (e < E) {
            d = __builtin_nontemporal_load(adj + E + e);
            if (d < lo || d >= hi) continue;
            s = __builtin_nontemporal_load(adj + e);
        } else {
            s = d = e - E;
            if (d < lo || d >= hi) continue;
        }
        int pos = atomicAdd(&cursor[d], 1);
        col_idx[pos] = s;
    }
}

// ---------------- dense pieces ----------------

__device__ __forceinline__ float bf_to_f(unsigned short u)
{
    return __uint_as_float((unsigned)u << 16);
}

// h = X @ W (h stored bf16); as[n]=h·a_src ; ad[n]=h·a_dst (f32 precision).
// 32 rows/block, 8 rows/wave, k-outer so each Ws element is reused across 8 rows.
template<int K>
__global__ __launch_bounds__(256) void gemm_alpha_kernel(
    const float* __restrict__ X, const float* __restrict__ W,
    const float* __restrict__ a_src, const float* __restrict__ a_dst,
    __hip_bfloat16* __restrict__ h, float* __restrict__ as_, float* __restrict__ ad_, int N)
{
    __shared__ float Ws[K * 64];
    __shared__ float Xs[32 * K];
    const int t = threadIdx.x;
    for (int i = t * 4; i < K * 64; i += 1024)
        *(float4*)(Ws + i) = *(const float4*)(W + i);
    const int row0 = blockIdx.x * 32;
    for (int i = t * 4; i < 32 * K; i += 1024) {
        int r = row0 + i / K;
        float4 v = make_float4(0.f, 0.f, 0.f, 0.f);
        if (r < N) v = *(const float4*)(X + (size_t)r * K + (i % K));
        *(float4*)(Xs + i) = v;
    }
    __syncthreads();
    const int wave = t >> 6, lane = t & 63;
    const float* xb = &Xs[wave * 8 * K];
    float acc[8] = {0.f, 0.f, 0.f, 0.f, 0.f, 0.f, 0.f, 0.f};
#pragma unroll 4
    for (int k4 = 0; k4 < K; k4 += 4) {
        float w0 = Ws[(k4 + 0) * 64 + lane];
        float w1 = Ws[(k4 + 1) * 64 + lane];
        float w2 = Ws[(k4 + 2) * 64 + lane];
        float w3 = Ws[(k4 + 3) * 64 + lane];
#pragma unroll
        for (int rr = 0; rr < 8; ++rr) {
            float4 xv = *(const float4*)(xb + rr * K + k4);
            acc[rr] += xv.x * w0 + xv.y * w1 + xv.z * w2 + xv.w * w3;
        }
    }
    const float a_s = a_src[lane], a_d = a_dst[lane];
#pragma unroll
    for (int rr = 0; rr < 8; ++rr) {
        int row = row0 + wave * 8 + rr;
        if (row >= N) break;
        float a = acc[rr];
        h[(size_t)row * 64 + lane] = __float2bfloat16(a);
        float va = a * a_s, vd = a * a_d;
#pragma unroll
        for (int off = 32; off > 0; off >>= 1) {
            va += __shfl_down(va, off, 64);
            vd += __shfl_down(vd, off, 64);
        }
        if (lane == 0) { as_[row] = va; ad_[row] = vd; }
    }
}

// Fused softmax+aggregate: one wave per dst node, 16 edges per loop step
// (4 sub-groups of 16 lanes x 4-deep unroll), bf16x4 (8B) loads over the 64-dim row.
__global__ __launch_bounds__(256) void gat_aggregate_kernel(
    const int* __restrict__ row_ptr, const int* __restrict__ col_idx,
    const float* __restrict__ as_, const float* __restrict__ ad_,
    const __hip_bfloat16* __restrict__ h, const float* __restrict__ b,
    float* __restrict__ out, int N, int do_elu)
{
    int node = blockIdx.x * 4 + (threadIdx.x >> 6);
    int lane = threadIdx.x & 63;
    int sub = lane >> 4, q = lane & 15;
    if (node >= N) return;
    int beg = row_ptr[node], end = row_ptr[node + 1];
    float ad = ad_[node];
    float4 acc = make_float4(0.f, 0.f, 0.f, 0.f);
    float psum = 0.f;
    const ushort4* hb = (const ushort4*)h;
    for (int i = beg; i < end; i += 16) {
        int e0 = i + sub, e1 = i + 4 + sub, e2 = i + 8 + sub, e3 = i + 12 + sub;
        bool v0 = e0 < end, v1 = e1 < end, v2 = e2 < end, v3 = e3 < end;
        int s0 = col_idx[v0 ? e0 : end - 1];
        int s1 = col_idx[v1 ? e1 : end - 1];
        int s2 = col_idx[v2 ? e2 : end - 1];
        int s3 = col_idx[v3 ? e3 : end - 1];
        float x0 = as_[s0] + ad, x1 = as_[s1] + ad;
        float x2 = as_[s2] + ad, x3 = as_[s3] + ad;
        ushort4 u0 = hb[(size_t)s0 * 16 + q];
        ushort4 u1 = hb[(size_t)s1 * 16 + q];
        ushort4 u2 = hb[(size_t)s2 * 16 + q];
        ushort4 u3 = hb[(size_t)s3 * 16 + q];
        x0 = x0 > 0.f ? x0 : NEG_SLOPE * x0;
        x1 = x1 > 0.f ? x1 : NEG_SLOPE * x1;
        x2 = x2 > 0.f ? x2 : NEG_SLOPE * x2;
        x3 = x3 > 0.f ? x3 : NEG_SLOPE * x3;
        float p0 = v0 ? __expf(x0) : 0.f;
        float p1 = v1 ? __expf(x1) : 0.f;
        float p2 = v2 ? __expf(x2) : 0.f;
        float p3 = v3 ? __expf(x3) : 0.f;
        psum += (p0 + p1) + (p2 + p3);
        acc.x += p0 * bf_to_f(u0.x) + p1 * bf_to_f(u1.x) + p2 * bf_to_f(u2.x) + p3 * bf_to_f(u3.x);
        acc.y += p0 * bf_to_f(u0.y) + p1 * bf_to_f(u1.y) + p2 * bf_to_f(u2.y) + p3 * bf_to_f(u3.y);
        acc.z += p0 * bf_to_f(u0.z) + p1 * bf_to_f(u1.z) + p2 * bf_to_f(u2.z) + p3 * bf_to_f(u3.z);
        acc.w += p0 * bf_to_f(u0.w) + p1 * bf_to_f(u1.w) + p2 * bf_to_f(u2.w) + p3 * bf_to_f(u3.w);
    }
#pragma unroll
    for (int off = 16; off <= 32; off <<= 1) {
        acc.x += __shfl_xor(acc.x, off, 64);
        acc.y += __shfl_xor(acc.y, off, 64);
        acc.z += __shfl_xor(acc.z, off, 64);
        acc.w += __shfl_xor(acc.w, off, 64);
        psum  += __shfl_xor(psum,  off, 64);
    }
    if (sub == 0) {
        float inv = 1.f / psum;
        float4 bb = ((const float4*)b)[q];
        float4 v;
        v.x = acc.x * inv + bb.x;
        v.y = acc.y * inv + bb.y;
        v.z = acc.z * inv + bb.z;
        v.w = acc.w * inv + bb.w;
        if (do_elu) {
            v.x = v.x > 0.f ? v.x : (__expf(v.x) - 1.f);
            v.y = v.y > 0.f ? v.y : (__expf(v.y) - 1.f);
            v.z = v.z > 0.f ? v.z : (__expf(v.z) - 1.f);
            v.w = v.w > 0.f ? v.w : (__expf(v.w) - 1.f);
        }
        ((float4*)(out + (size_t)node * 64))[q] = v;
    }
}

// logits[n][c] = x[n]·cW[:,c] + cb[c]
__global__ __launch_bounds__(256) void classifier_kernel(
    const float* __restrict__ x, const float* __restrict__ cw,
    const float* __restrict__ cb, float* __restrict__ out, int N)
{
    int i = blockIdx.x * blockDim.x + threadIdx.x;
    if (i >= N * 16) return;
    int n = i >> 4, c = i & 15;
    const float4* xr = (const float4*)(x + (size_t)n * 64);
    float acc = cb[c];
#pragma unroll
    for (int j4 = 0; j4 < 16; ++j4) {
        float4 xv = xr[j4];
        acc += xv.x * cw[(j4 * 4 + 0) * 16 + c];
        acc += xv.y * cw[(j4 * 4 + 1) * 16 + c];
        acc += xv.z * cw[(j4 * 4 + 2) * 16 + c];
        acc += xv.w * cw[(j4 * 4 + 3) * 16 + c];
    }
    out[i] = acc;
}

extern "C" void kernel_launch(void* const* d_in, const int* in_sizes, int n_in,
                              void* d_out, int out_size, void* d_ws, size_t ws_size,
                              hipStream_t stream)
{
    const float* X    = (const float*)d_in[0];
    const int*   adj  = (const int*)d_in[1];
    const float* W1   = (const float*)d_in[2];
    const float* a_s1 = (const float*)d_in[3];
    const float* a_d1 = (const float*)d_in[4];
    const float* b1   = (const float*)d_in[5];
    const float* W2   = (const float*)d_in[6];
    const float* a_s2 = (const float*)d_in[7];
    const float* a_d2 = (const float*)d_in[8];
    const float* b2   = (const float*)d_in[9];
    const float* cW   = (const float*)d_in[10];
    const float* cb   = (const float*)d_in[11];

    const int N  = in_sizes[0] / 128;
    const int E  = in_sizes[1] / 2;
    const int ET = E + N;
    const int NB = (N + 1023) / 1024;
    const int W  = (N + NSLICE - 1) / NSLICE;   // dst-slice width

    __hip_bfloat16* A = (__hip_bfloat16*)d_ws;        // h (bf16), N*64
    float* B       = (float*)(A + (size_t)N * 64);    // layer1 x, N*64 f32
    float* asb     = B + (size_t)N * 64;              // N
    float* adb     = asb + N;                         // N
    int*   deg     = (int*)(adb + N);                 // N
    int*   cursor  = deg + N;                         // N
    int*   row_ptr = cursor + N;                      // N+1
    int*   col_idx = row_ptr + (N + 1);               // E+N
    int*   bsum    = col_idx + ET;                    // NB (<=1024)

    const int T = 256;
    const int nodeBlocks  = (N + T - 1) / T;
    const int gemmBlocks  = (N + 31) / 32;
    const int aggBlocks   = (N + 3) / 4;

    // ---- CSR build (once, reused by both layers) ----
    init_deg_kernel<<<nodeBlocks, T, 0, stream>>>(deg, N);
    count_deg_sliced_kernel<<<SCAT_GRID, T, 0, stream>>>(adj, deg, E, N, W);
    scan1_kernel<<<NB, 1024, 0, stream>>>(deg, row_ptr, bsum, N);
    scan2_kernel<<<1, 1024, 0, stream>>>(bsum, NB);
    scan3_kernel<<<nodeBlocks, T, 0, stream>>>(row_ptr, cursor, deg, bsum, N);
    scatter_sliced_kernel<<<SCAT_GRID, T, 0, stream>>>(adj, cursor, col_idx, E, N, W);

    // ---- layer 1 ----
    gemm_alpha_kernel<128><<<gemmBlocks, T, 0, stream>>>(
        X, W1, a_s1, a_d1, A, asb, adb, N);
    gat_aggregate_kernel<<<aggBlocks, T, 0, stream>>>(
        row_ptr, col_idx, asb, adb, A, b1, B, N, 1);

    // ---- layer 2 (x written straight into d_out tail) ----
    float* out  = (float*)d_out;
    float* xout = out + (size_t)N * 16;
    gemm_alpha_kernel<64><<<gemmBlocks, T, 0, stream>>>(
        B, W2, a_s2, a_d2, A, asb, adb, N);
    gat_aggregate_kernel<<<aggBlocks, T, 0, stream>>>(
        row_ptr, col_idx, asb, adb, A, b2, xout, N, 0);

    // ---- classifier ----
    classifier_kernel<<<(N * 16 + T - 1) / T, T, 0, stream>>>(
        xout, cW, cb, out, N);
}

// Round 8
// 470.998 us; speedup vs baseline: 1.5275x; 1.0633x over previous
//
#include <hip/hip_runtime.h>
#include <hip/hip_bf16.h>

#define NEG_SLOPE 0.2f
#define BSH 9                    // 512 dst nodes per bucket
#define BW  (1 << BSH)
#define CH  4096                 // edges per partition round
#define PGRID 256                // workgroups for A0/A1

// ================= radix CSR build (no global atomics) =================

// A0: per-round bucket histogram. H[r*NBK + b] = #edges of round r in bucket b.
__global__ __launch_bounds__(256) void bucket_hist_kernel(
    const int* __restrict__ adj, int* __restrict__ H, int E, int N, int R, int NBK)
{
    __shared__ int hist[256];
    const int t = threadIdx.x;
    const int ET = E + N;
    for (int r = blockIdx.x; r < R; r += gridDim.x) {
        hist[t] = 0;
        __syncthreads();
        int base = r * CH;
        for (int i = 0; i < CH / 256; ++i) {
            int e = base + i * 256 + t;
            if (e >= ET) break;
            int d = (e < E) ? adj[E + e] : (e - E);
            atomicAdd(&hist[d >> BSH], 1);
        }
        __syncthreads();
        if (t < NBK) H[r * NBK + t] = hist[t];
        __syncthreads();
    }
}

// Exclusive scan of H in bucket-major order (f = b*R + r); result stored
// transposed: S2[r*NBK + b]. Single workgroup, 1024 threads.
__global__ __launch_bounds__(1024) void scan_hist_kernel(
    const int* __restrict__ H, int* __restrict__ S2, int R, int NBK)
{
    __shared__ int psum[1024];
    const int t = threadIdx.x;
    const int F = R * NBK;
    const int C = (F + 1023) / 1024;
    int f0 = t * C, f1 = min(F, f0 + C);
    int s = 0;
    for (int f = f0; f < f1; ++f) {
        int b = f / R, r = f - b * R;
        s += H[r * NBK + b];
    }
    psum[t] = s;
    __syncthreads();
    for (int off = 1; off < 1024; off <<= 1) {
        int v = (t >= off) ? psum[t - off] : 0;
        __syncthreads();
        psum[t] += v;
        __syncthreads();
    }
    int run = (t > 0) ? psum[t - 1] : 0;
    for (int f = f0; f < f1; ++f) {
        int b = f / R, r = f - b * R;
        int idx = r * NBK + b;
        int h = H[idx];
        S2[idx] = run;
        run += h;
    }
}

// A1: scatter edges into bucket-grouped pbuf at precomputed offsets.
// pbuf entry = (src << BSH) | (dst & (BW-1)).  src < 2^17, so fits in 26 bits.
__global__ __launch_bounds__(256) void partition_kernel(
    const int* __restrict__ adj, const int* __restrict__ S2,
    int* __restrict__ pbuf, int E, int N, int R, int NBK)
{
    __shared__ int lcur[256];
    const int t = threadIdx.x;
    const int ET = E + N;
    for (int r = blockIdx.x; r < R; r += gridDim.x) {
        if (t < NBK) lcur[t] = S2[r * NBK + t];
        __syncthreads();
        int base = r * CH;
        for (int i = 0; i < CH / 256; ++i) {
            int e = base + i * 256 + t;
            if (e >= ET) break;
            int s, d;
            if (e < E) { d = adj[E + e]; s = adj[e]; }
            else       { s = d = e - E; }
            int b = d >> BSH;
            int pos = atomicAdd(&lcur[b], 1);
            pbuf[pos] = (s << BSH) | (d & (BW - 1));
        }
        __syncthreads();
    }
}

// B: one WG per bucket. LDS hist over 512 local nodes + LDS scan ->
// row_ptr window AND node-grouped col_idx, all inside a ~35KB L2-local window.
__global__ __launch_bounds__(256) void csr_build_kernel(
    const int* __restrict__ S2, const int* __restrict__ pbuf,
    int* __restrict__ row_ptr, int* __restrict__ col_idx, int E, int N, int NBK)
{
    __shared__ int offA[BW];
    __shared__ int lcur[BW];
    const int b = blockIdx.x;
    const int t = threadIdx.x;
    const int node0 = b << BSH;
    const int nn = min(BW, N - node0);
    const int ET = E + N;
    const int segbeg = S2[b];                       // S2[r=0][b] = bucket start
    const int segend = (b == NBK - 1) ? ET : S2[b + 1];

    offA[t] = 0; offA[t + 256] = 0;
    __syncthreads();
    for (int i = segbeg + t; i < segend; i += 256)
        atomicAdd(&offA[pbuf[i] & (BW - 1)], 1);
    __syncthreads();
    // inclusive Hillis-Steele scan over 512 elements (2 per thread)
    for (int off = 1; off < BW; off <<= 1) {
        int i1 = t + 256;
        int v0 = (t >= off) ? offA[t - off] : 0;
        int v1 = (i1 >= off) ? offA[i1 - off] : 0;
        __syncthreads();
        offA[t] += v0; offA[i1] += v1;
        __syncthreads();
    }
    if (t < nn) {
        int ex = t ? offA[t - 1] : 0;
        row_ptr[node0 + t] = segbeg + ex;
        lcur[t] = segbeg + ex;
    }
    int i2 = t + 256;
    if (i2 < nn) {
        int ex = offA[i2 - 1];
        row_ptr[node0 + i2] = segbeg + ex;
        lcur[i2] = segbeg + ex;
    }
    if (b == NBK - 1 && t == 0) row_ptr[N] = ET;
    __syncthreads();
    for (int i = segbeg + t; i < segend; i += 256) {
        int p = pbuf[i];
        int pos = atomicAdd(&lcur[p & (BW - 1)], 1);
        col_idx[pos] = p >> BSH;
    }
}

// ================= dense pieces =================

__device__ __forceinline__ float bf_to_f(unsigned short u)
{
    return __uint_as_float((unsigned)u << 16);
}

// h = X @ W (h stored bf16); as[n]=h·a_src ; ad[n]=h·a_dst (f32 precision).
// 32 rows/block, 8 rows/wave, k-outer so each Ws element is reused across 8 rows.
template<int K>
__global__ __launch_bounds__(256) void gemm_alpha_kernel(
    const float* __restrict__ X, const float* __restrict__ W,
    const float* __restrict__ a_src, const float* __restrict__ a_dst,
    __hip_bfloat16* __restrict__ h, float* __restrict__ as_, float* __restrict__ ad_, int N)
{
    __shared__ float Ws[K * 64];
    __shared__ float Xs[32 * K];
    const int t = threadIdx.x;
    for (int i = t * 4; i < K * 64; i += 1024)
        *(float4*)(Ws + i) = *(const float4*)(W + i);
    const int row0 = blockIdx.x * 32;
    for (int i = t * 4; i < 32 * K; i += 1024) {
        int r = row0 + i / K;
        float4 v = make_float4(0.f, 0.f, 0.f, 0.f);
        if (r < N) v = *(const float4*)(X + (size_t)r * K + (i % K));
        *(float4*)(Xs + i) = v;
    }
    __syncthreads();
    const int wave = t >> 6, lane = t & 63;
    const float* xb = &Xs[wave * 8 * K];
    float acc[8] = {0.f, 0.f, 0.f, 0.f, 0.f, 0.f, 0.f, 0.f};
#pragma unroll 4
    for (int k4 = 0; k4 < K; k4 += 4) {
        float w0 = Ws[(k4 + 0) * 64 + lane];
        float w1 = Ws[(k4 + 1) * 64 + lane];
        float w2 = Ws[(k4 + 2) * 64 + lane];
        float w3 = Ws[(k4 + 3) * 64 + lane];
#pragma unroll
        for (int rr = 0; rr < 8; ++rr) {
            float4 xv = *(const float4*)(xb + rr * K + k4);
            acc[rr] += xv.x * w0 + xv.y * w1 + xv.z * w2 + xv.w * w3;
        }
    }
    const float a_s = a_src[lane], a_d = a_dst[lane];
#pragma unroll
    for (int rr = 0; rr < 8; ++rr) {
        int row = row0 + wave * 8 + rr;
        if (row >= N) break;
        float a = acc[rr];
        h[(size_t)row * 64 + lane] = __float2bfloat16(a);
        float va = a * a_s, vd = a * a_d;
#pragma unroll
        for (int off = 32; off > 0; off >>= 1) {
            va += __shfl_down(va, off, 64);
            vd += __shfl_down(vd, off, 64);
        }
        if (lane == 0) { as_[row] = va; ad_[row] = vd; }
    }
}

// Fused softmax+aggregate: one wave per dst node, 16 edges per loop step
// (4 sub-groups of 16 lanes x 4-deep unroll), bf16x4 (8B) loads over the 64-dim row.
__global__ __launch_bounds__(256) void gat_aggregate_kernel(
    const int* __restrict__ row_ptr, const int* __restrict__ col_idx,
    const float* __restrict__ as_, const float* __restrict__ ad_,
    const __hip_bfloat16* __restrict__ h, const float* __restrict__ b,
    float* __restrict__ out, int N, int do_elu)
{
    int node = blockIdx.x * 4 + (threadIdx.x >> 6);
    int lane = threadIdx.x & 63;
    int sub = lane >> 4, q = lane & 15;
    if (node >= N) return;
    int beg = row_ptr[node], end = row_ptr[node + 1];
    float ad = ad_[node];
    float4 acc = make_float4(0.f, 0.f, 0.f, 0.f);
    float psum = 0.f;
    const ushort4* hb = (const ushort4*)h;
    for (int i = beg; i < end; i += 16) {
        int e0 = i + sub, e1 = i + 4 + sub, e2 = i + 8 + sub, e3 = i + 12 + sub;
        bool v0 = e0 < end, v1 = e1 < end, v2 = e2 < end, v3 = e3 < end;
        int s0 = col_idx[v0 ? e0 : end - 1];
        int s1 = col_idx[v1 ? e1 : end - 1];
        int s2 = col_idx[v2 ? e2 : end - 1];
        int s3 = col_idx[v3 ? e3 : end - 1];
        float x0 = as_[s0] + ad, x1 = as_[s1] + ad;
        float x2 = as_[s2] + ad, x3 = as_[s3] + ad;
        ushort4 u0 = hb[(size_t)s0 * 16 + q];
        ushort4 u1 = hb[(size_t)s1 * 16 + q];
        ushort4 u2 = hb[(size_t)s2 * 16 + q];
        ushort4 u3 = hb[(size_t)s3 * 16 + q];
        x0 = x0 > 0.f ? x0 : NEG_SLOPE * x0;
        x1 = x1 > 0.f ? x1 : NEG_SLOPE * x1;
        x2 = x2 > 0.f ? x2 : NEG_SLOPE * x2;
        x3 = x3 > 0.f ? x3 : NEG_SLOPE * x3;
        float p0 = v0 ? __expf(x0) : 0.f;
        float p1 = v1 ? __expf(x1) : 0.f;
        float p2 = v2 ? __expf(x2) : 0.f;
        float p3 = v3 ? __expf(x3) : 0.f;
        psum += (p0 + p1) + (p2 + p3);
        acc.x += p0 * bf_to_f(u0.x) + p1 * bf_to_f(u1.x) + p2 * bf_to_f(u2.x) + p3 * bf_to_f(u3.x);
        acc.y += p0 * bf_to_f(u0.y) + p1 * bf_to_f(u1.y) + p2 * bf_to_f(u2.y) + p3 * bf_to_f(u3.y);
        acc.z += p0 * bf_to_f(u0.z) + p1 * bf_to_f(u1.z) + p2 * bf_to_f(u2.z) + p3 * bf_to_f(u3.z);
        acc.w += p0 * bf_to_f(u0.w) + p1 * bf_to_f(u1.w) + p2 * bf_to_f(u2.w) + p3 * bf_to_f(u3.w);
    }
#pragma unroll
    for (int off = 16; off <= 32; off <<= 1) {
        acc.x += __shfl_xor(acc.x, off, 64);
        acc.y += __shfl_xor(acc.y, off, 64);
        acc.z += __shfl_xor(acc.z, off, 64);
        acc.w += __shfl_xor(acc.w, off, 64);
        psum  += __shfl_xor(psum,  off, 64);
    }
    if (sub == 0) {
        float inv = 1.f / psum;
        float4 bb = ((const float4*)b)[q];
        float4 v;
        v.x = acc.x * inv + bb.x;
        v.y = acc.y * inv + bb.y;
        v.z = acc.z * inv + bb.z;
        v.w = acc.w * inv + bb.w;
        if (do_elu) {
            v.x = v.x > 0.f ? v.x : (__expf(v.x) - 1.f);
            v.y = v.y > 0.f ? v.y : (__expf(v.y) - 1.f);
            v.z = v.z > 0.f ? v.z : (__expf(v.z) - 1.f);
            v.w = v.w > 0.f ? v.w : (__expf(v.w) - 1.f);
        }
        ((float4*)(out + (size_t)node * 64))[q] = v;
    }
}

// logits[n][c] = x[n]·cW[:,c] + cb[c]
__global__ __launch_bounds__(256) void classifier_kernel(
    const float* __restrict__ x, const float* __restrict__ cw,
    const float* __restrict__ cb, float* __restrict__ out, int N)
{
    int i = blockIdx.x * blockDim.x + threadIdx.x;
    if (i >= N * 16) return;
    int n = i >> 4, c = i & 15;
    const float4* xr = (const float4*)(x + (size_t)n * 64);
    float acc = cb[c];
#pragma unroll
    for (int j4 = 0; j4 < 16; ++j4) {
        float4 xv = xr[j4];
        acc += xv.x * cw[(j4 * 4 + 0) * 16 + c];
        acc += xv.y * cw[(j4 * 4 + 1) * 16 + c];
        acc += xv.z * cw[(j4 * 4 + 2) * 16 + c];
        acc += xv.w * cw[(j4 * 4 + 3) * 16 + c];
    }
    out[i] = acc;
}

extern "C" void kernel_launch(void* const* d_in, const int* in_sizes, int n_in,
                              void* d_out, int out_size, void* d_ws, size_t ws_size,
                              hipStream_t stream)
{
    const float* X    = (const float*)d_in[0];
    const int*   adj  = (const int*)d_in[1];
    const float* W1   = (const float*)d_in[2];
    const float* a_s1 = (const float*)d_in[3];
    const float* a_d1 = (const float*)d_in[4];
    const float* b1   = (const float*)d_in[5];
    const float* W2   = (const float*)d_in[6];
    const float* a_s2 = (const float*)d_in[7];
    const float* a_d2 = (const float*)d_in[8];
    const float* b2   = (const float*)d_in[9];
    const float* cW   = (const float*)d_in[10];
    const float* cb   = (const float*)d_in[11];

    const int N   = in_sizes[0] / 128;
    const int E   = in_sizes[1] / 2;
    const int ET  = E + N;
    const int R   = (ET + CH - 1) / CH;           // partition rounds
    const int NBK = (N + BW - 1) >> BSH;          // buckets (<=256)

    __hip_bfloat16* A = (__hip_bfloat16*)d_ws;        // h (bf16), N*64
    float* B       = (float*)(A + (size_t)N * 64);    // layer1 x, N*64 f32
    float* asb     = B + (size_t)N * 64;              // N
    float* adb     = asb + N;                         // N
    int*   row_ptr = (int*)(adb + N);                 // N+1
    int*   col_idx = row_ptr + (N + 1);               // ET
    int*   pbuf    = col_idx + ET;                    // ET
    int*   H       = pbuf + ET;                       // R*NBK
    int*   S2      = H + R * NBK;                     // R*NBK

    const int T = 256;
    const int gemmBlocks = (N + 31) / 32;
    const int aggBlocks  = (N + 3) / 4;

    // ---- radix CSR build (once, reused by both layers) ----
    bucket_hist_kernel<<<PGRID, T, 0, stream>>>(adj, H, E, N, R, NBK);
    scan_hist_kernel<<<1, 1024, 0, stream>>>(H, S2, R, NBK);
    partition_kernel<<<PGRID, T, 0, stream>>>(adj, S2, pbuf, E, N, R, NBK);
    csr_build_kernel<<<NBK, T, 0, stream>>>(S2, pbuf, row_ptr, col_idx, E, N, NBK);

    // ---- layer 1 ----
    gemm_alpha_kernel<128><<<gemmBlocks, T, 0, stream>>>(
        X, W1, a_s1, a_d1, A, asb, adb, N);
    gat_aggregate_kernel<<<aggBlocks, T, 0, stream>>>(
        row_ptr, col_idx, asb, adb, A, b1, B, N, 1);

    // ---- layer 2 (x written straight into d_out tail) ----
    float* out  = (float*)d_out;
    float* xout = out + (size_t)N * 16;
    gemm_alpha_kernel<64><<<gemmBlocks, T, 0, stream>>>(
        B, W2, a_s2, a_d2, A, asb, adb, N);
    gat_aggregate_kernel<<<aggBlocks, T, 0, stream>>>(
        row_ptr, col_idx, asb, adb, A, b2, xout, N, 0);

    // ---- classifier ----
    classifier_kernel<<<(N * 16 + T - 1) / T, T, 0, stream>>>(
        xout, cW, cb, out, N);
}

// Round 9
// 389.288 us; speedup vs baseline: 1.8481x; 1.2099x over previous
//
#include <hip/hip_runtime.h>
#include <hip/hip_bf16.h>

#define NEG_SLOPE 0.2f
#define BSH 9                    // 512 dst nodes per bucket
#define BW  (1 << BSH)
#define CH  4096                 // edges per partition round
#define PGRID 256                // workgroups for A0/A1

// ================= radix CSR build (no global atomics) =================

// A0: per-round bucket histogram. H[r*NBK + b] = #edges of round r in bucket b.
__global__ __launch_bounds__(256) void bucket_hist_kernel(
    const int* __restrict__ adj, int* __restrict__ H, int E, int N, int R, int NBK)
{
    __shared__ int hist[256];
    const int t = threadIdx.x;
    const int ET = E + N;
    for (int r = blockIdx.x; r < R; r += gridDim.x) {
        hist[t] = 0;
        __syncthreads();
        int base = r * CH;
        for (int i = 0; i < CH / 256; ++i) {
            int e = base + i * 256 + t;
            if (e >= ET) break;
            int d = (e < E) ? adj[E + e] : (e - E);
            atomicAdd(&hist[d >> BSH], 1);
        }
        __syncthreads();
        if (t < NBK) H[r * NBK + t] = hist[t];
        __syncthreads();
    }
}

// Per-bucket scan over rounds (196 blocks in parallel):
// S2[r][b] = sum_{r'<r} H[r'][b]  (within-bucket prefix), tot[b] = bucket total.
__global__ __launch_bounds__(256) void scan_rounds_kernel(
    const int* __restrict__ H, int* __restrict__ S2, int* __restrict__ tot,
    int R, int NBK)
{
    __shared__ int part[256];
    const int b = blockIdx.x;
    const int t = threadIdx.x;
    const int C = (R + 255) / 256;
    int r0 = t * C, r1 = min(R, r0 + C);
    int s = 0;
    for (int r = r0; r < r1; ++r) s += H[r * NBK + b];
    part[t] = s;
    __syncthreads();
    for (int off = 1; off < 256; off <<= 1) {
        int v = (t >= off) ? part[t - off] : 0;
        __syncthreads();
        part[t] += v;
        __syncthreads();
    }
    int run = (t > 0) ? part[t - 1] : 0;
    for (int r = r0; r < r1; ++r) {
        int h = H[r * NBK + b];
        S2[r * NBK + b] = run;
        run += h;
    }
    if (t == 255) tot[b] = part[255];
}

// Exclusive scan of bucket totals -> base[b]. One block; NBK <= 256.
__global__ __launch_bounds__(256) void scan_tot_kernel(
    const int* __restrict__ tot, int* __restrict__ base, int NBK)
{
    __shared__ int s[256];
    int t = threadIdx.x;
    int v = (t < NBK) ? tot[t] : 0;
    s[t] = v;
    __syncthreads();
    for (int off = 1; off < 256; off <<= 1) {
        int u = (t >= off) ? s[t - off] : 0;
        __syncthreads();
        s[t] += u;
        __syncthreads();
    }
    if (t < NBK) base[t] = s[t] - v;
}

// A1: scatter edges into bucket-grouped pbuf at precomputed offsets.
// pbuf entry = (src << BSH) | (dst & (BW-1)).  src < 2^17, fits in 23+9 bits.
__global__ __launch_bounds__(256) void partition_kernel(
    const int* __restrict__ adj, const int* __restrict__ S2,
    const int* __restrict__ base, int* __restrict__ pbuf,
    int E, int N, int R, int NBK)
{
    __shared__ int lcur[256];
    const int t = threadIdx.x;
    const int ET = E + N;
    for (int r = blockIdx.x; r < R; r += gridDim.x) {
        if (t < NBK) lcur[t] = base[t] + S2[r * NBK + t];
        __syncthreads();
        int b0 = r * CH;
        for (int i = 0; i < CH / 256; ++i) {
            int e = b0 + i * 256 + t;
            if (e >= ET) break;
            int s, d;
            if (e < E) { d = adj[E + e]; s = adj[e]; }
            else       { s = d = e - E; }
            int b = d >> BSH;
            int pos = atomicAdd(&lcur[b], 1);
            pbuf[pos] = (s << BSH) | (d & (BW - 1));
        }
        __syncthreads();
    }
}

// B: one WG per bucket. LDS hist over 512 local nodes + LDS scan ->
// row_ptr window AND node-grouped col_idx, all inside a ~35KB L2-local window.
__global__ __launch_bounds__(256) void csr_build_kernel(
    const int* __restrict__ base, const int* __restrict__ tot,
    const int* __restrict__ pbuf,
    int* __restrict__ row_ptr, int* __restrict__ col_idx, int E, int N, int NBK)
{
    __shared__ int offA[BW];
    __shared__ int lcur[BW];
    const int b = blockIdx.x;
    const int t = threadIdx.x;
    const int node0 = b << BSH;
    const int nn = min(BW, N - node0);
    const int ET = E + N;
    const int segbeg = base[b];
    const int segend = segbeg + tot[b];

    offA[t] = 0; offA[t + 256] = 0;
    __syncthreads();
    for (int i = segbeg + t; i < segend; i += 256)
        atomicAdd(&offA[pbuf[i] & (BW - 1)], 1);
    __syncthreads();
    // inclusive Hillis-Steele scan over 512 elements (2 per thread)
    for (int off = 1; off < BW; off <<= 1) {
        int i1 = t + 256;
        int v0 = (t >= off) ? offA[t - off] : 0;
        int v1 = (i1 >= off) ? offA[i1 - off] : 0;
        __syncthreads();
        offA[t] += v0; offA[i1] += v1;
        __syncthreads();
    }
    if (t < nn) {
        int ex = t ? offA[t - 1] : 0;
        row_ptr[node0 + t] = segbeg + ex;
        lcur[t] = segbeg + ex;
    }
    int i2 = t + 256;
    if (i2 < nn) {
        int ex = offA[i2 - 1];
        row_ptr[node0 + i2] = segbeg + ex;
        lcur[i2] = segbeg + ex;
    }
    if (b == NBK - 1 && t == 0) row_ptr[N] = ET;
    __syncthreads();
    for (int i = segbeg + t; i < segend; i += 256) {
        int p = pbuf[i];
        int pos = atomicAdd(&lcur[p & (BW - 1)], 1);
        col_idx[pos] = p >> BSH;
    }
}

// ================= dense pieces =================

__device__ __forceinline__ float bf_to_f(unsigned short u)
{
    return __uint_as_float((unsigned)u << 16);
}

// h = X @ W (h stored bf16); as[n]=h·a_src ; ad[n]=h·a_dst (f32 precision).
// 32 rows/block, 8 rows/wave, k-outer so each Ws element is reused across 8 rows.
template<int K>
__global__ __launch_bounds__(256) void gemm_alpha_kernel(
    const float* __restrict__ X, const float* __restrict__ W,
    const float* __restrict__ a_src, const float* __restrict__ a_dst,
    __hip_bfloat16* __restrict__ h, float* __restrict__ as_, float* __restrict__ ad_, int N)
{
    __shared__ float Ws[K * 64];
    __shared__ float Xs[32 * K];
    const int t = threadIdx.x;
    for (int i = t * 4; i < K * 64; i += 1024)
        *(float4*)(Ws + i) = *(const float4*)(W + i);
    const int row0 = blockIdx.x * 32;
    for (int i = t * 4; i < 32 * K; i += 1024) {
        int r = row0 + i / K;
        float4 v = make_float4(0.f, 0.f, 0.f, 0.f);
        if (r < N) v = *(const float4*)(X + (size_t)r * K + (i % K));
        *(float4*)(Xs + i) = v;
    }
    __syncthreads();
    const int wave = t >> 6, lane = t & 63;
    const float* xb = &Xs[wave * 8 * K];
    float acc[8] = {0.f, 0.f, 0.f, 0.f, 0.f, 0.f, 0.f, 0.f};
#pragma unroll 4
    for (int k4 = 0; k4 < K; k4 += 4) {
        float w0 = Ws[(k4 + 0) * 64 + lane];
        float w1 = Ws[(k4 + 1) * 64 + lane];
        float w2 = Ws[(k4 + 2) * 64 + lane];
        float w3 = Ws[(k4 + 3) * 64 + lane];
#pragma unroll
        for (int rr = 0; rr < 8; ++rr) {
            float4 xv = *(const float4*)(xb + rr * K + k4);
            acc[rr] += xv.x * w0 + xv.y * w1 + xv.z * w2 + xv.w * w3;
        }
    }
    const float a_s = a_src[lane], a_d = a_dst[lane];
#pragma unroll
    for (int rr = 0; rr < 8; ++rr) {
        int row = row0 + wave * 8 + rr;
        if (row >= N) break;
        float a = acc[rr];
        h[(size_t)row * 64 + lane] = __float2bfloat16(a);
        float va = a * a_s, vd = a * a_d;
#pragma unroll
        for (int off = 32; off > 0; off >>= 1) {
            va += __shfl_down(va, off, 64);
            vd += __shfl_down(vd, off, 64);
        }
        if (lane == 0) { as_[row] = va; ad_[row] = vd; }
    }
}

// Fused softmax+aggregate: one wave per dst node, 16 edges per loop step
// (4 sub-groups of 16 lanes x 4-deep unroll), bf16x4 (8B) loads over the 64-dim row.
__global__ __launch_bounds__(256) void gat_aggregate_kernel(
    const int* __restrict__ row_ptr, const int* __restrict__ col_idx,
    const float* __restrict__ as_, const float* __restrict__ ad_,
    const __hip_bfloat16* __restrict__ h, const float* __restrict__ b,
    float* __restrict__ out, int N, int do_elu)
{
    int node = blockIdx.x * 4 + (threadIdx.x >> 6);
    int lane = threadIdx.x & 63;
    int sub = lane >> 4, q = lane & 15;
    if (node >= N) return;
    int beg = row_ptr[node], end = row_ptr[node + 1];
    float ad = ad_[node];
    float4 acc = make_float4(0.f, 0.f, 0.f, 0.f);
    float psum = 0.f;
    const ushort4* hb = (const ushort4*)h;
    for (int i = beg; i < end; i += 16) {
        int e0 = i + sub, e1 = i + 4 + sub, e2 = i + 8 + sub, e3 = i + 12 + sub;
        bool v0 = e0 < end, v1 = e1 < end, v2 = e2 < end, v3 = e3 < end;
        int s0 = col_idx[v0 ? e0 : end - 1];
        int s1 = col_idx[v1 ? e1 : end - 1];
        int s2 = col_idx[v2 ? e2 : end - 1];
        int s3 = col_idx[v3 ? e3 : end - 1];
        float x0 = as_[s0] + ad, x1 = as_[s1] + ad;
        float x2 = as_[s2] + ad, x3 = as_[s3] + ad;
        ushort4 u0 = hb[(size_t)s0 * 16 + q];
        ushort4 u1 = hb[(size_t)s1 * 16 + q];
        ushort4 u2 = hb[(size_t)s2 * 16 + q];
        ushort4 u3 = hb[(size_t)s3 * 16 + q];
        x0 = x0 > 0.f ? x0 : NEG_SLOPE * x0;
        x1 = x1 > 0.f ? x1 : NEG_SLOPE * x1;
        x2 = x2 > 0.f ? x2 : NEG_SLOPE * x2;
        x3 = x3 > 0.f ? x3 : NEG_SLOPE * x3;
        float p0 = v0 ? __expf(x0) : 0.f;
        float p1 = v1 ? __expf(x1) : 0.f;
        float p2 = v2 ? __expf(x2) : 0.f;
        float p3 = v3 ? __expf(x3) : 0.f;
        psum += (p0 + p1) + (p2 + p3);
        acc.x += p0 * bf_to_f(u0.x) + p1 * bf_to_f(u1.x) + p2 * bf_to_f(u2.x) + p3 * bf_to_f(u3.x);
        acc.y += p0 * bf_to_f(u0.y) + p1 * bf_to_f(u1.y) + p2 * bf_to_f(u2.y) + p3 * bf_to_f(u3.y);
        acc.z += p0 * bf_to_f(u0.z) + p1 * bf_to_f(u1.z) + p2 * bf_to_f(u2.z) + p3 * bf_to_f(u3.z);
        acc.w += p0 * bf_to_f(u0.w) + p1 * bf_to_f(u1.w) + p2 * bf_to_f(u2.w) + p3 * bf_to_f(u3.w);
    }
#pragma unroll
    for (int off = 16; off <= 32; off <<= 1) {
        acc.x += __shfl_xor(acc.x, off, 64);
        acc.y += __shfl_xor(acc.y, off, 64);
        acc.z += __shfl_xor(acc.z, off, 64);
        acc.w += __shfl_xor(acc.w, off, 64);
        psum  += __shfl_xor(psum,  off, 64);
    }
    if (sub == 0) {
        float inv = 1.f / psum;
        float4 bb = ((const float4*)b)[q];
        float4 v;
        v.x = acc.x * inv + bb.x;
        v.y = acc.y * inv + bb.y;
        v.z = acc.z * inv + bb.z;
        v.w = acc.w * inv + bb.w;
        if (do_elu) {
            v.x = v.x > 0.f ? v.x : (__expf(v.x) - 1.f);
            v.y = v.y > 0.f ? v.y : (__expf(v.y) - 1.f);
            v.z = v.z > 0.f ? v.z : (__expf(v.z) - 1.f);
            v.w = v.w > 0.f ? v.w : (__expf(v.w) - 1.f);
        }
        ((float4*)(out + (size_t)node * 64))[q] = v;
    }
}

// logits[n][c] = x[n]·cW[:,c] + cb[c]
__global__ __launch_bounds__(256) void classifier_kernel(
    const float* __restrict__ x, const float* __restrict__ cw,
    const float* __restrict__ cb, float* __restrict__ out, int N)
{
    int i = blockIdx.x * blockDim.x + threadIdx.x;
    if (i >= N * 16) return;
    int n = i >> 4, c = i & 15;
    const float4* xr = (const float4*)(x + (size_t)n * 64);
    float acc = cb[c];
#pragma unroll
    for (int j4 = 0; j4 < 16; ++j4) {
        float4 xv = xr[j4];
        acc += xv.x * cw[(j4 * 4 + 0) * 16 + c];
        acc += xv.y * cw[(j4 * 4 + 1) * 16 + c];
        acc += xv.z * cw[(j4 * 4 + 2) * 16 + c];
        acc += xv.w * cw[(j4 * 4 + 3) * 16 + c];
    }
    out[i] = acc;
}

extern "C" void kernel_launch(void* const* d_in, const int* in_sizes, int n_in,
                              void* d_out, int out_size, void* d_ws, size_t ws_size,
                              hipStream_t stream)
{
    const float* X    = (const float*)d_in[0];
    const int*   adj  = (const int*)d_in[1];
    const float* W1   = (const float*)d_in[2];
    const float* a_s1 = (const float*)d_in[3];
    const float* a_d1 = (const float*)d_in[4];
    const float* b1   = (const float*)d_in[5];
    const float* W2   = (const float*)d_in[6];
    const float* a_s2 = (const float*)d_in[7];
    const float* a_d2 = (const float*)d_in[8];
    const float* b2   = (const float*)d_in[9];
    const float* cW   = (const float*)d_in[10];
    const float* cb   = (const float*)d_in[11];

    const int N   = in_sizes[0] / 128;
    const int E   = in_sizes[1] / 2;
    const int ET  = E + N;
    const int R   = (ET + CH - 1) / CH;           // partition rounds
    const int NBK = (N + BW - 1) >> BSH;          // buckets (<=256)

    __hip_bfloat16* A = (__hip_bfloat16*)d_ws;        // h (bf16), N*64
    float* B       = (float*)(A + (size_t)N * 64);    // layer1 x, N*64 f32
    float* asb     = B + (size_t)N * 64;              // N
    float* adb     = asb + N;                         // N
    int*   row_ptr = (int*)(adb + N);                 // N+1
    int*   col_idx = row_ptr + (N + 1);               // ET
    int*   pbuf    = col_idx + ET;                    // ET
    int*   H       = pbuf + ET;                       // R*NBK
    int*   S2      = H + R * NBK;                     // R*NBK
    int*   tot     = S2 + R * NBK;                    // NBK
    int*   base    = tot + NBK;                       // NBK

    const int T = 256;
    const int gemmBlocks = (N + 31) / 32;
    const int aggBlocks  = (N + 3) / 4;

    // ---- radix CSR build (once, reused by both layers) ----
    bucket_hist_kernel<<<PGRID, T, 0, stream>>>(adj, H, E, N, R, NBK);
    scan_rounds_kernel<<<NBK, T, 0, stream>>>(H, S2, tot, R, NBK);
    scan_tot_kernel<<<1, T, 0, stream>>>(tot, base, NBK);
    partition_kernel<<<PGRID, T, 0, stream>>>(adj, S2, base, pbuf, E, N, R, NBK);
    csr_build_kernel<<<NBK, T, 0, stream>>>(base, tot, pbuf, row_ptr, col_idx, E, N, NBK);

    // ---- layer 1 ----
    gemm_alpha_kernel<128><<<gemmBlocks, T, 0, stream>>>(
        X, W1, a_s1, a_d1, A, asb, adb, N);
    gat_aggregate_kernel<<<aggBlocks, T, 0, stream>>>(
        row_ptr, col_idx, asb, adb, A, b1, B, N, 1);

    // ---- layer 2 (x written straight into d_out tail) ----
    float* out  = (float*)d_out;
    float* xout = out + (size_t)N * 16;
    gemm_alpha_kernel<64><<<gemmBlocks, T, 0, stream>>>(
        B, W2, a_s2, a_d2, A, asb, adb, N);
    gat_aggregate_kernel<<<aggBlocks, T, 0, stream>>>(
        row_ptr, col_idx, asb, adb, A, b2, xout, N, 0);

    // ---- classifier ----
    classifier_kernel<<<(N * 16 + T - 1) / T, T, 0, stream>>>(
        xout, cW, cb, out, N);
}